// Round 12
// baseline (521.599 us; speedup 1.0000x reference)
//
#include <hip/hip_runtime.h>

#define NN 100000
#define NE 1600000
#define D1 128
#define D2 64
#define BN_EPS 1e-5f
#define SCAN_CHUNK 512
#define NB_SCAN ((NN + SCAN_CHUNK - 1) / SCAN_CHUNK)   // 196
#define NB_WT   ((128 * 128 + 64 * 128 + 255) / 256)    // 96
#define NB_FILL (NE / 512)                              // 3125 (2 edges/thread)
#define NB_G1   ((NN + 63) / 64)                        // 1563

typedef unsigned int uint32;
typedef unsigned short ushort;
typedef __attribute__((ext_vector_type(8))) short bf16x8;
typedef __attribute__((ext_vector_type(4))) float f32x4;

// ---- bf16 helpers (RNE) ----
__device__ __forceinline__ ushort f2bf1(float f) {
    uint32 u = __float_as_uint(f);
    return (ushort)((u + 0x7FFFu + ((u >> 16) & 1u)) >> 16);
}
__device__ __forceinline__ uint32 f2bf_pair(float a, float b) {
    uint32 ua = __float_as_uint(a), ub = __float_as_uint(b);
    ua = (ua + 0x7FFFu + ((ua >> 16) & 1u)) >> 16;
    ub = (ub + 0x7FFFu + ((ub >> 16) & 1u)) >> 16;
    return ua | (ub << 16);
}
__device__ __forceinline__ float bf_lo(uint32 v) { return __uint_as_float(v << 16); }
__device__ __forceinline__ float bf_hi(uint32 v) { return __uint_as_float(v & 0xFFFF0000u); }

// ---------------- fused: W transpose+bf16 (blocks 0..NB_WT) ∥ degree count ----------------
__global__ __launch_bounds__(256) void wtcnt_k(const float* __restrict__ W1,
                                               const float* __restrict__ W2,
                                               ushort* __restrict__ wt1,
                                               ushort* __restrict__ wt2,
                                               const int* __restrict__ dst,
                                               int* __restrict__ cnt) {
    if (blockIdx.x < NB_WT) {
        int i = blockIdx.x * 256 + threadIdx.x;
        if (i < 128 * 128) {
            int c = i >> 7, k = i & 127;
            wt1[i] = f2bf1(W1[k * 128 + c]);
        } else if (i < 128 * 128 + 64 * 128) {
            int o = i - 128 * 128;
            int c = o >> 7, k = o & 127;
            wt2[o] = f2bf1(W2[k * 64 + c]);
        }
        return;
    }
    int i = (blockIdx.x - NB_WT) * 256 + threadIdx.x;
    int2 dd = *(const int2*)&dst[2 * i];
    atomicAdd(&cnt[dd.x], 1);
    atomicAdd(&cnt[dd.y], 1);
}

// ---------------- prefix scan part 1; also emits dis = rsqrt(cnt+1) ----------------
__global__ __launch_bounds__(SCAN_CHUNK) void scan1_k(const int* __restrict__ cnt,
                                                      int* __restrict__ rowptr,
                                                      int* __restrict__ bsum,
                                                      float* __restrict__ dis) {
    __shared__ int sh[SCAN_CHUNK];
    int tid = threadIdx.x;
    int g = blockIdx.x * SCAN_CHUNK + tid;
    int v = (g < NN) ? cnt[g] : 0;
    if (g < NN) dis[g] = rsqrtf((float)v + 1.0f);
    sh[tid] = v;
    __syncthreads();
    for (int o = 1; o < SCAN_CHUNK; o <<= 1) {
        int t = (tid >= o) ? sh[tid - o] : 0;
        __syncthreads();
        sh[tid] += t;
        __syncthreads();
    }
    if (g < NN) rowptr[g] = sh[tid] - v;
    if (tid == SCAN_CHUNK - 1) bsum[blockIdx.x] = sh[tid];
}

// ---------------- prefix scan part 2+3 fused ----------------
__global__ __launch_bounds__(256) void scan23_k(int* __restrict__ rowptr,
                                                const int* __restrict__ bsum) {
    __shared__ int bs[256];
    int tid = threadIdx.x;
    bs[tid] = (tid < NB_SCAN) ? bsum[tid] : 0;
    __syncthreads();
    for (int o = 1; o < 256; o <<= 1) {
        int t = (tid >= o) ? bs[tid - o] : 0;
        __syncthreads();
        bs[tid] += t;
        __syncthreads();
    }
    int g = blockIdx.x * 256 + tid;
    if (g < NN) {
        int chunk = g >> 9;
        int add = (chunk == 0) ? 0 : bs[chunk - 1];
        rowptr[g] += add;
    }
    if (g == 0) rowptr[NN] = NE;
}

// ---------------- fused dispatch: CSR fill (esrc only) ∥ MFMA GEMM layer1 ----------------
__global__ __launch_bounds__(256) void fillgemm_k(const int* __restrict__ src,
                                                  const int* __restrict__ dst,
                                                  const int* __restrict__ rowptr,
                                                  int* __restrict__ cur,
                                                  int* __restrict__ esrc,
                                                  const float* __restrict__ X,
                                                  const ushort* __restrict__ Wt,
                                                  ushort* __restrict__ Yb) {
    if (blockIdx.x < NB_FILL) {
        int i = blockIdx.x * 256 + threadIdx.x;
        int2 ss = *(const int2*)&src[2 * i];
        int2 dd = *(const int2*)&dst[2 * i];
        int p0 = rowptr[dd.x] + atomicAdd(&cur[dd.x], 1);
        esrc[p0] = ss.x;
        int p1 = rowptr[dd.y] + atomicAdd(&cur[dd.y], 1);
        esrc[p1] = ss.y;
        return;
    }
    // ---- mgemm1 body ----
    const int bid = blockIdx.x - NB_FILL;
    const int lane = threadIdx.x & 63;
    const int wv = threadIdx.x >> 6;
    const int row0 = bid * 64 + wv * 16;
    const int m = lane & 15;
    const int kg = lane >> 4;
    const int rowA = min(row0 + m, NN - 1);
    f32x4 acc[8];
    #pragma unroll
    for (int t = 0; t < 8; ++t) acc[t] = (f32x4){0.f, 0.f, 0.f, 0.f};

    #pragma unroll
    for (int kc = 0; kc < 128; kc += 32) {
        const int k0 = kc + kg * 8;
        float4 xa = *(const float4*)(X + (size_t)rowA * 128 + k0);
        float4 xb = *(const float4*)(X + (size_t)rowA * 128 + k0 + 4);
        bf16x8 af;
        af[0] = (short)f2bf1(xa.x); af[1] = (short)f2bf1(xa.y);
        af[2] = (short)f2bf1(xa.z); af[3] = (short)f2bf1(xa.w);
        af[4] = (short)f2bf1(xb.x); af[5] = (short)f2bf1(xb.y);
        af[6] = (short)f2bf1(xb.z); af[7] = (short)f2bf1(xb.w);
        #pragma unroll
        for (int t = 0; t < 8; ++t) {
            bf16x8 bfr = *(const bf16x8*)(Wt + (size_t)(t * 16 + m) * 128 + k0);
            acc[t] = __builtin_amdgcn_mfma_f32_16x16x32_bf16(af, bfr, acc[t], 0, 0, 0);
        }
    }
    #pragma unroll
    for (int t = 0; t < 8; ++t)
        #pragma unroll
        for (int r = 0; r < 4; ++r) {
            int rr = row0 + kg * 4 + r;
            if (rr < NN) Yb[(size_t)rr * 128 + t * 16 + m] = f2bf1(acc[t][r]);
        }
}

// ---------------- MFMA GEMM layer2: frozen R10 ----------------
__global__ __launch_bounds__(256) void mgemm2_k(const ushort* __restrict__ Xb,
                                                const ushort* __restrict__ Wt,
                                                const float* __restrict__ sums,
                                                const float* __restrict__ ssq,
                                                const float* __restrict__ g,
                                                const float* __restrict__ beta,
                                                ushort* __restrict__ Yb) {
    __shared__ float sc[128], shf[128];
    {
        int t = threadIdx.x;
        if (t < 128) {
            float m = sums[t] * (1.0f / NN);
            float var = ssq[t] * (1.0f / NN) - m * m;
            float s = g[t] * rsqrtf(var + BN_EPS);
            sc[t] = s;
            shf[t] = beta[t] - m * s;
        }
    }
    __syncthreads();
    const int lane = threadIdx.x & 63;
    const int wv = threadIdx.x >> 6;
    const int row0 = blockIdx.x * 64 + wv * 16;
    const int m = lane & 15;
    const int kg = lane >> 4;
    const int rowA = min(row0 + m, NN - 1);
    f32x4 acc[4];
    #pragma unroll
    for (int t = 0; t < 4; ++t) acc[t] = (f32x4){0.f, 0.f, 0.f, 0.f};

    #pragma unroll
    for (int kc = 0; kc < 128; kc += 32) {
        const int k0 = kc + kg * 8;
        uint4 raw = *(const uint4*)(Xb + (size_t)rowA * 128 + k0);
        float xs[8];
        xs[0] = bf_lo(raw.x); xs[1] = bf_hi(raw.x);
        xs[2] = bf_lo(raw.y); xs[3] = bf_hi(raw.y);
        xs[4] = bf_lo(raw.z); xs[5] = bf_hi(raw.z);
        xs[6] = bf_lo(raw.w); xs[7] = bf_hi(raw.w);
        float4 sa = *(const float4*)&sc[k0];
        float4 sb = *(const float4*)&sc[k0 + 4];
        float4 ha = *(const float4*)&shf[k0];
        float4 hb = *(const float4*)&shf[k0 + 4];
        xs[0] = fmaxf(fmaf(xs[0], sa.x, ha.x), 0.f);
        xs[1] = fmaxf(fmaf(xs[1], sa.y, ha.y), 0.f);
        xs[2] = fmaxf(fmaf(xs[2], sa.z, ha.z), 0.f);
        xs[3] = fmaxf(fmaf(xs[3], sa.w, ha.w), 0.f);
        xs[4] = fmaxf(fmaf(xs[4], sb.x, hb.x), 0.f);
        xs[5] = fmaxf(fmaf(xs[5], sb.y, hb.y), 0.f);
        xs[6] = fmaxf(fmaf(xs[6], sb.z, hb.z), 0.f);
        xs[7] = fmaxf(fmaf(xs[7], sb.w, hb.w), 0.f);
        bf16x8 af;
        #pragma unroll
        for (int i = 0; i < 8; ++i) af[i] = (short)f2bf1(xs[i]);
        #pragma unroll
        for (int t = 0; t < 4; ++t) {
            bf16x8 bfr = *(const bf16x8*)(Wt + (size_t)(t * 16 + m) * 128 + k0);
            acc[t] = __builtin_amdgcn_mfma_f32_16x16x32_bf16(af, bfr, acc[t], 0, 0, 0);
        }
    }
    #pragma unroll
    for (int t = 0; t < 4; ++t)
        #pragma unroll
        for (int r = 0; r < 4; ++r) {
            int rr = row0 + kg * 4 + r;
            if (rr < NN) Yb[(size_t)rr * 64 + t * 16 + m] = f2bf1(acc[t][r]);
        }
}

// ---------------- agg layer1 (D=128): R10 structure; w recomputed from dis ----------------
__global__ __launch_bounds__(256) void agg128_k(const int* __restrict__ rowptr,
                                                const int* __restrict__ esrc,
                                                const float* __restrict__ dis,
                                                const uint32* __restrict__ xwb,
                                                const float* __restrict__ b,
                                                uint32* __restrict__ agg1b,
                                                float* __restrict__ sums,
                                                float* __restrict__ ssq) {
    const int lane = threadIdx.x & 63;
    const int wid = (blockIdx.x * 256 + threadIdx.x) >> 6;
    const int nwaves = gridDim.x * 4;
    float s0 = 0.f, s1 = 0.f, q0 = 0.f, q1 = 0.f;
    const float bc0 = b[lane * 2], bc1 = b[lane * 2 + 1];

    for (int n = wid; n < NN; n += nwaves) {
        const int beg = rowptr[n], end = rowptr[n + 1];
        const float dn = dis[n];
        float ax = 0.f, ay = 0.f;
        int e = beg;
        for (; e + 8 <= end; e += 8) {
            int idx[8]; uint32 vv[8]; float w[8];
            #pragma unroll
            for (int j = 0; j < 8; ++j) idx[j] = esrc[e + j];
            #pragma unroll
            for (int j = 0; j < 8; ++j)
                vv[j] = xwb[(size_t)idx[j] * 64 + lane];
            #pragma unroll
            for (int j = 0; j < 8; ++j) w[j] = dis[idx[j]] * dn;
            #pragma unroll
            for (int j = 0; j < 8; ++j) {
                ax = fmaf(bf_lo(vv[j]), w[j], ax);
                ay = fmaf(bf_hi(vv[j]), w[j], ay);
            }
        }
        for (; e < end; ++e) {
            int s = esrc[e];
            float w = dis[s] * dn;
            uint32 v = xwb[(size_t)s * 64 + lane];
            ax = fmaf(bf_lo(v), w, ax);
            ay = fmaf(bf_hi(v), w, ay);
        }
        float sl = dn * dn;  // self-loop norm 1/(deg+1)
        uint32 xv = xwb[(size_t)n * 64 + lane];
        ax = fmaf(bf_lo(xv), sl, ax) + bc0;
        ay = fmaf(bf_hi(xv), sl, ay) + bc1;
        agg1b[(size_t)n * 64 + lane] = f2bf_pair(ax, ay);
        s0 += ax; q0 = fmaf(ax, ax, q0);
        s1 += ay; q1 = fmaf(ay, ay, q1);
    }

    __shared__ float ls[256];
    ls[threadIdx.x] = 0.f;
    __syncthreads();
    atomicAdd(&ls[lane * 2], s0);
    atomicAdd(&ls[lane * 2 + 1], s1);
    atomicAdd(&ls[128 + lane * 2], q0);
    atomicAdd(&ls[128 + lane * 2 + 1], q1);
    __syncthreads();
    if (threadIdx.x < 128) atomicAdd(&sums[threadIdx.x], ls[threadIdx.x]);
    else atomicAdd(&ssq[threadIdx.x - 128], ls[threadIdx.x]);
}

// ---------------- agg layer2 (D=64): R10 structure; w recomputed from dis ----------------
__global__ __launch_bounds__(256) void agg64_k(const int* __restrict__ rowptr,
                                               const int* __restrict__ esrc,
                                               const float* __restrict__ dis,
                                               const uint32* __restrict__ xwb,  // 32 uint32/row
                                               const float* __restrict__ b,
                                               uint32* __restrict__ agg2b,
                                               float* __restrict__ sums,
                                               float* __restrict__ ssq) {
    const int lane = threadIdx.x & 63;
    const int half = lane >> 5;
    const int sl = lane & 31;
    const int wid = (blockIdx.x * 256 + threadIdx.x) >> 6;
    const int nwaves = gridDim.x * 4;
    float s0 = 0.f, s1 = 0.f, q0 = 0.f, q1 = 0.f;
    const float bc0 = b[sl * 2], bc1 = b[sl * 2 + 1];

    for (int n = wid; n < NN; n += nwaves) {
        const int beg = rowptr[n], end = rowptr[n + 1];
        const float dn = dis[n];
        float ax = 0.f, ay = 0.f;
        int e = beg;
        for (; e + 16 <= end; e += 16) {
            int idx[8]; uint32 vv[8]; float w[8];
            #pragma unroll
            for (int j = 0; j < 8; ++j) idx[j] = esrc[e + 2 * j + half];
            #pragma unroll
            for (int j = 0; j < 8; ++j)
                vv[j] = xwb[(size_t)idx[j] * 32 + sl];
            #pragma unroll
            for (int j = 0; j < 8; ++j) w[j] = dis[idx[j]] * dn;
            #pragma unroll
            for (int j = 0; j < 8; ++j) {
                ax = fmaf(bf_lo(vv[j]), w[j], ax);
                ay = fmaf(bf_hi(vv[j]), w[j], ay);
            }
        }
        for (; e + 2 <= end; e += 2) {
            int s = esrc[e + half];
            float w = dis[s] * dn;
            uint32 v = xwb[(size_t)s * 32 + sl];
            ax = fmaf(bf_lo(v), w, ax);
            ay = fmaf(bf_hi(v), w, ay);
        }
        if (e < end && half == 0) {
            int s = esrc[e];
            float w = dis[s] * dn;
            uint32 v = xwb[(size_t)s * 32 + sl];
            ax = fmaf(bf_lo(v), w, ax);
            ay = fmaf(bf_hi(v), w, ay);
        }
        ax += __shfl_down(ax, 32);
        ay += __shfl_down(ay, 32);
        if (half == 0) {
            float slf = dn * dn;
            uint32 xv = xwb[(size_t)n * 32 + sl];
            ax = fmaf(bf_lo(xv), slf, ax) + bc0;
            ay = fmaf(bf_hi(xv), slf, ay) + bc1;
            agg2b[(size_t)n * 32 + sl] = f2bf_pair(ax, ay);
            s0 += ax; q0 = fmaf(ax, ax, q0);
            s1 += ay; q1 = fmaf(ay, ay, q1);
        }
    }

    __shared__ float ls[128];
    if (threadIdx.x < 128) ls[threadIdx.x] = 0.f;
    __syncthreads();
    if (half == 0) {
        atomicAdd(&ls[sl * 2], s0);
        atomicAdd(&ls[sl * 2 + 1], s1);
        atomicAdd(&ls[64 + sl * 2], q0);
        atomicAdd(&ls[64 + sl * 2 + 1], q1);
    }
    __syncthreads();
    if (threadIdx.x < 64) atomicAdd(&sums[threadIdx.x], ls[threadIdx.x]);
    else if (threadIdx.x < 128) atomicAdd(&ssq[threadIdx.x - 64], ls[threadIdx.x]);
}

// ---------------- final: frozen R10 ----------------
__global__ __launch_bounds__(256) void final_k(const uint32* __restrict__ h2b,
                                               const float* __restrict__ sums,
                                               const float* __restrict__ ssq,
                                               const float* __restrict__ g,
                                               const float* __restrict__ beta,
                                               const float* __restrict__ Wf,
                                               const float* __restrict__ bf,
                                               float* __restrict__ out) {
    __shared__ float sc[64], shf[64];
    {
        int t = threadIdx.x;
        if (t < 64) {
            float m = sums[t] * (1.0f / NN);
            float var = ssq[t] * (1.0f / NN) - m * m;
            float s = g[t] * rsqrtf(var + BN_EPS);
            sc[t] = s;
            shf[t] = beta[t] - m * s;
        }
    }
    __syncthreads();
    const int lane = threadIdx.x & 63;
    const int half = lane >> 5;
    const int sl = lane & 31;
    const int node = ((blockIdx.x * 256 + threadIdx.x) >> 6) * 2 + half;
    if (node >= NN) return;
    uint32 p = h2b[(size_t)node * 32 + sl];
    float2 wf = *(const float2*)&Wf[sl * 2];
    float v = fmaxf(fmaf(bf_lo(p), sc[sl * 2], shf[sl * 2]), 0.f) * wf.x;
    v = fmaf(fmaxf(fmaf(bf_hi(p), sc[sl * 2 + 1], shf[sl * 2 + 1]), 0.f), wf.y, v);
    #pragma unroll
    for (int o = 16; o > 0; o >>= 1) v += __shfl_down(v, o, 32);
    if (sl == 0) out[node] = v + bf[0];
}

extern "C" void kernel_launch(void* const* d_in, const int* in_sizes, int n_in,
                              void* d_out, int out_size, void* d_ws, size_t ws_size,
                              hipStream_t stream) {
    const float* x   = (const float*)d_in[0];
    const int*   ei  = (const int*)d_in[1];
    const int*   src = ei;
    const int*   dst = ei + NE;
    const float* W1  = (const float*)d_in[2];
    const float* b1  = (const float*)d_in[3];
    const float* g1  = (const float*)d_in[4];
    const float* be1 = (const float*)d_in[5];
    const float* W2  = (const float*)d_in[6];
    const float* b2  = (const float*)d_in[7];
    const float* g2  = (const float*)d_in[8];
    const float* be2 = (const float*)d_in[9];
    const float* Wf  = (const float*)d_in[10];
    const float* bf  = (const float*)d_in[11];
    float* out = (float*)d_out;

    // ---- workspace layout ----
    uint32* xwb   = (uint32*)d_ws;                     // NN*64 u32 (bf16 xw, both layers)
    uint32* agg1b = xwb + (size_t)NN * 64;             // NN*64 u32 (bf16 h1 pre-BN)
    uint32* agg2b = agg1b + (size_t)NN * 64;           // NN*32 u32 (bf16 h2 pre-BN)
    float*  dis   = (float*)(agg2b + (size_t)NN * 32); // NN
    ushort* wt1   = (ushort*)(dis + NN);               // 128*128 bf16
    ushort* wt2   = wt1 + 128 * 128;                   // 64*128 bf16
    int*    rowptr = (int*)(wt2 + 64 * 128);           // NN+1
    int*    bsum   = rowptr + NN + 1;                  // 256
    int*    esrc   = bsum + 256;                       // NE
    int*    cnt    = esrc + NE;                        // NN
    int*    cur    = cnt + NN;                         // NN
    float*  sums1  = (float*)(cur + NN);               // 128
    float*  ssq1   = sums1 + D1;                       // 128
    float*  sums2  = ssq1 + D1;                        // 64
    float*  ssq2   = sums2 + D2;                       // 64

    hipMemsetAsync(cnt, 0, sizeof(int) * (2 * NN + 2 * D1 + 2 * D2), stream);

    // ---- weight prep ∥ degree count, then scan ----
    wtcnt_k<<<NB_WT + NE / 512, 256, 0, stream>>>(W1, W2, wt1, wt2, dst, cnt);
    scan1_k<<<NB_SCAN, SCAN_CHUNK, 0, stream>>>(cnt, rowptr, bsum, dis);
    scan23_k<<<(NN + 255) / 256, 256, 0, stream>>>(rowptr, bsum);

    // ---- fill ∥ layer-1 GEMM ----
    fillgemm_k<<<NB_FILL + NB_G1, 256, 0, stream>>>(src, dst, rowptr, cur, esrc,
                                                    x, wt1, (ushort*)xwb);

    // ---- layer 1 aggregate ----
    agg128_k<<<2048, 256, 0, stream>>>(rowptr, esrc, dis, xwb, b1, agg1b, sums1, ssq1);

    // ---- layer 2 ----
    mgemm2_k<<<(NN + 63) / 64, 256, 0, stream>>>((const ushort*)agg1b, wt2, sums1, ssq1,
                                                 g1, be1, (ushort*)xwb);
    agg64_k<<<2048, 256, 0, stream>>>(rowptr, esrc, dis, xwb, b2, agg2b, sums2, ssq2);

    // ---- final projection ----
    final_k<<<(NN / 2 + 3) / 4, 256, 0, stream>>>(agg2b, sums2, ssq2, g2, be2, Wf, bf, out);
}

// Round 13
// 447.379 us; speedup vs baseline: 1.1659x; 1.1659x over previous
//
#include <hip/hip_runtime.h>

#define NN 100000
#define NE 1600000
#define D1 128
#define D2 64
#define BN_EPS 1e-5f
#define SCAN_CHUNK 512
#define NB_SCAN ((NN + SCAN_CHUNK - 1) / SCAN_CHUNK)   // 196
#define NB_WT   ((128 * 128 + 64 * 128 + 255) / 256)    // 96
#define NB_FILL (NE / 512)                              // 3125 (2 edges/thread)
#define NB_G1   ((NN + 63) / 64)                        // 1563

typedef unsigned int uint32;
typedef unsigned long long u64;
typedef unsigned short ushort;
typedef __attribute__((ext_vector_type(8))) short bf16x8;
typedef __attribute__((ext_vector_type(4))) float f32x4;

// ---- bf16 helpers (RNE) ----
__device__ __forceinline__ ushort f2bf1(float f) {
    uint32 u = __float_as_uint(f);
    return (ushort)((u + 0x7FFFu + ((u >> 16) & 1u)) >> 16);
}
__device__ __forceinline__ uint32 f2bf_pair(float a, float b) {
    uint32 ua = __float_as_uint(a), ub = __float_as_uint(b);
    ua = (ua + 0x7FFFu + ((ua >> 16) & 1u)) >> 16;
    ub = (ub + 0x7FFFu + ((ub >> 16) & 1u)) >> 16;
    return ua | (ub << 16);
}
__device__ __forceinline__ float bf_lo(uint32 v) { return __uint_as_float(v << 16); }
__device__ __forceinline__ float bf_hi(uint32 v) { return __uint_as_float(v & 0xFFFF0000u); }

// ---------------- fused: W transpose+bf16 (blocks 0..NB_WT) ∥ degree count ----------------
__global__ __launch_bounds__(256) void wtcnt_k(const float* __restrict__ W1,
                                               const float* __restrict__ W2,
                                               ushort* __restrict__ wt1,
                                               ushort* __restrict__ wt2,
                                               const int* __restrict__ dst,
                                               int* __restrict__ cnt) {
    if (blockIdx.x < NB_WT) {
        int i = blockIdx.x * 256 + threadIdx.x;
        if (i < 128 * 128) {
            int c = i >> 7, k = i & 127;
            wt1[i] = f2bf1(W1[k * 128 + c]);
        } else if (i < 128 * 128 + 64 * 128) {
            int o = i - 128 * 128;
            int c = o >> 7, k = o & 127;
            wt2[o] = f2bf1(W2[k * 64 + c]);
        }
        return;
    }
    int i = (blockIdx.x - NB_WT) * 256 + threadIdx.x;
    int2 dd = *(const int2*)&dst[2 * i];
    atomicAdd(&cnt[dd.x], 1);
    atomicAdd(&cnt[dd.y], 1);
}

// ---------------- prefix scan part 1; also emits dis = rsqrt(cnt+1) ----------------
__global__ __launch_bounds__(SCAN_CHUNK) void scan1_k(const int* __restrict__ cnt,
                                                      int* __restrict__ rowptr,
                                                      int* __restrict__ bsum,
                                                      float* __restrict__ dis) {
    __shared__ int sh[SCAN_CHUNK];
    int tid = threadIdx.x;
    int g = blockIdx.x * SCAN_CHUNK + tid;
    int v = (g < NN) ? cnt[g] : 0;
    if (g < NN) dis[g] = rsqrtf((float)v + 1.0f);
    sh[tid] = v;
    __syncthreads();
    for (int o = 1; o < SCAN_CHUNK; o <<= 1) {
        int t = (tid >= o) ? sh[tid - o] : 0;
        __syncthreads();
        sh[tid] += t;
        __syncthreads();
    }
    if (g < NN) rowptr[g] = sh[tid] - v;
    if (tid == SCAN_CHUNK - 1) bsum[blockIdx.x] = sh[tid];
}

// ---------------- prefix scan part 2+3 fused ----------------
__global__ __launch_bounds__(256) void scan23_k(int* __restrict__ rowptr,
                                                const int* __restrict__ bsum) {
    __shared__ int bs[256];
    int tid = threadIdx.x;
    bs[tid] = (tid < NB_SCAN) ? bsum[tid] : 0;
    __syncthreads();
    for (int o = 1; o < 256; o <<= 1) {
        int t = (tid >= o) ? bs[tid - o] : 0;
        __syncthreads();
        bs[tid] += t;
        __syncthreads();
    }
    int g = blockIdx.x * 256 + tid;
    if (g < NN) {
        int chunk = g >> 9;
        int add = (chunk == 0) ? 0 : bs[chunk - 1];
        rowptr[g] += add;
    }
    if (g == 0) rowptr[NN] = NE;
}

// ---------------- fused dispatch: CSR fill (packed u64, ONE scattered store/edge) ∥ mgemm1 ----------------
__global__ __launch_bounds__(256) void fillgemm_k(const int* __restrict__ src,
                                                  const int* __restrict__ dst,
                                                  const int* __restrict__ rowptr,
                                                  const float* __restrict__ dis,
                                                  int* __restrict__ cur,
                                                  u64* __restrict__ edges,
                                                  const float* __restrict__ X,
                                                  const ushort* __restrict__ Wt,
                                                  ushort* __restrict__ Yb) {
    if (blockIdx.x < NB_FILL) {
        int i = blockIdx.x * 256 + threadIdx.x;
        int2 ss = *(const int2*)&src[2 * i];
        int2 dd = *(const int2*)&dst[2 * i];
        u64 pk0 = ((u64)__float_as_uint(dis[ss.x] * dis[dd.x]) << 32) | (uint32)ss.x;
        int p0 = rowptr[dd.x] + atomicAdd(&cur[dd.x], 1);
        edges[p0] = pk0;
        u64 pk1 = ((u64)__float_as_uint(dis[ss.y] * dis[dd.y]) << 32) | (uint32)ss.y;
        int p1 = rowptr[dd.y] + atomicAdd(&cur[dd.y], 1);
        edges[p1] = pk1;
        return;
    }
    // ---- mgemm1 body ----
    const int bid = blockIdx.x - NB_FILL;
    const int lane = threadIdx.x & 63;
    const int wv = threadIdx.x >> 6;
    const int row0 = bid * 64 + wv * 16;
    const int m = lane & 15;
    const int kg = lane >> 4;
    const int rowA = min(row0 + m, NN - 1);
    f32x4 acc[8];
    #pragma unroll
    for (int t = 0; t < 8; ++t) acc[t] = (f32x4){0.f, 0.f, 0.f, 0.f};

    #pragma unroll
    for (int kc = 0; kc < 128; kc += 32) {
        const int k0 = kc + kg * 8;
        float4 xa = *(const float4*)(X + (size_t)rowA * 128 + k0);
        float4 xb = *(const float4*)(X + (size_t)rowA * 128 + k0 + 4);
        bf16x8 af;
        af[0] = (short)f2bf1(xa.x); af[1] = (short)f2bf1(xa.y);
        af[2] = (short)f2bf1(xa.z); af[3] = (short)f2bf1(xa.w);
        af[4] = (short)f2bf1(xb.x); af[5] = (short)f2bf1(xb.y);
        af[6] = (short)f2bf1(xb.z); af[7] = (short)f2bf1(xb.w);
        #pragma unroll
        for (int t = 0; t < 8; ++t) {
            bf16x8 bfr = *(const bf16x8*)(Wt + (size_t)(t * 16 + m) * 128 + k0);
            acc[t] = __builtin_amdgcn_mfma_f32_16x16x32_bf16(af, bfr, acc[t], 0, 0, 0);
        }
    }
    #pragma unroll
    for (int t = 0; t < 8; ++t)
        #pragma unroll
        for (int r = 0; r < 4; ++r) {
            int rr = row0 + kg * 4 + r;
            if (rr < NN) Yb[(size_t)rr * 128 + t * 16 + m] = f2bf1(acc[t][r]);
        }
}

// ---------------- MFMA GEMM layer2: frozen R10 ----------------
__global__ __launch_bounds__(256) void mgemm2_k(const ushort* __restrict__ Xb,
                                                const ushort* __restrict__ Wt,
                                                const float* __restrict__ sums,
                                                const float* __restrict__ ssq,
                                                const float* __restrict__ g,
                                                const float* __restrict__ beta,
                                                ushort* __restrict__ Yb) {
    __shared__ float sc[128], shf[128];
    {
        int t = threadIdx.x;
        if (t < 128) {
            float m = sums[t] * (1.0f / NN);
            float var = ssq[t] * (1.0f / NN) - m * m;
            float s = g[t] * rsqrtf(var + BN_EPS);
            sc[t] = s;
            shf[t] = beta[t] - m * s;
        }
    }
    __syncthreads();
    const int lane = threadIdx.x & 63;
    const int wv = threadIdx.x >> 6;
    const int row0 = blockIdx.x * 64 + wv * 16;
    const int m = lane & 15;
    const int kg = lane >> 4;
    const int rowA = min(row0 + m, NN - 1);
    f32x4 acc[4];
    #pragma unroll
    for (int t = 0; t < 4; ++t) acc[t] = (f32x4){0.f, 0.f, 0.f, 0.f};

    #pragma unroll
    for (int kc = 0; kc < 128; kc += 32) {
        const int k0 = kc + kg * 8;
        uint4 raw = *(const uint4*)(Xb + (size_t)rowA * 128 + k0);
        float xs[8];
        xs[0] = bf_lo(raw.x); xs[1] = bf_hi(raw.x);
        xs[2] = bf_lo(raw.y); xs[3] = bf_hi(raw.y);
        xs[4] = bf_lo(raw.z); xs[5] = bf_hi(raw.z);
        xs[6] = bf_lo(raw.w); xs[7] = bf_hi(raw.w);
        float4 sa = *(const float4*)&sc[k0];
        float4 sb = *(const float4*)&sc[k0 + 4];
        float4 ha = *(const float4*)&shf[k0];
        float4 hb = *(const float4*)&shf[k0 + 4];
        xs[0] = fmaxf(fmaf(xs[0], sa.x, ha.x), 0.f);
        xs[1] = fmaxf(fmaf(xs[1], sa.y, ha.y), 0.f);
        xs[2] = fmaxf(fmaf(xs[2], sa.z, ha.z), 0.f);
        xs[3] = fmaxf(fmaf(xs[3], sa.w, ha.w), 0.f);
        xs[4] = fmaxf(fmaf(xs[4], sb.x, hb.x), 0.f);
        xs[5] = fmaxf(fmaf(xs[5], sb.y, hb.y), 0.f);
        xs[6] = fmaxf(fmaf(xs[6], sb.z, hb.z), 0.f);
        xs[7] = fmaxf(fmaf(xs[7], sb.w, hb.w), 0.f);
        bf16x8 af;
        #pragma unroll
        for (int i = 0; i < 8; ++i) af[i] = (short)f2bf1(xs[i]);
        #pragma unroll
        for (int t = 0; t < 4; ++t) {
            bf16x8 bfr = *(const bf16x8*)(Wt + (size_t)(t * 16 + m) * 128 + k0);
            acc[t] = __builtin_amdgcn_mfma_f32_16x16x32_bf16(af, bfr, acc[t], 0, 0, 0);
        }
    }
    #pragma unroll
    for (int t = 0; t < 4; ++t)
        #pragma unroll
        for (int r = 0; r < 4; ++r) {
            int rr = row0 + kg * 4 + r;
            if (rr < NN) Yb[(size_t)rr * 64 + t * 16 + m] = f2bf1(acc[t][r]);
        }
}

// ---------------- agg layer1 (D=128): packed edges, masked-tail full-width batches ----------------
__global__ __launch_bounds__(256) void agg128_k(const int* __restrict__ rowptr,
                                                const u64* __restrict__ edges,
                                                const float* __restrict__ dis,
                                                const uint32* __restrict__ xwb,
                                                const float* __restrict__ b,
                                                uint32* __restrict__ agg1b,
                                                float* __restrict__ sums,
                                                float* __restrict__ ssq) {
    const int lane = threadIdx.x & 63;
    const int wid = (blockIdx.x * 256 + threadIdx.x) >> 6;
    const int nwaves = gridDim.x * 4;
    float s0 = 0.f, s1 = 0.f, q0 = 0.f, q1 = 0.f;
    const float bc0 = b[lane * 2], bc1 = b[lane * 2 + 1];

    for (int n = wid; n < NN; n += nwaves) {
        const int beg = rowptr[n], end = rowptr[n + 1];
        const float dn = dis[n];
        float ax = 0.f, ay = 0.f;
        for (int e = beg; e < end; e += 8) {
            u64 ed[8]; uint32 vv[8]; float w[8];
            #pragma unroll
            for (int j = 0; j < 8; ++j) ed[j] = edges[min(e + j, end - 1)];
            #pragma unroll
            for (int j = 0; j < 8; ++j)
                vv[j] = xwb[(size_t)(uint32)ed[j] * 64 + lane];
            #pragma unroll
            for (int j = 0; j < 8; ++j)
                w[j] = (e + j < end) ? __uint_as_float((uint32)(ed[j] >> 32)) : 0.f;
            #pragma unroll
            for (int j = 0; j < 8; ++j) {
                ax = fmaf(bf_lo(vv[j]), w[j], ax);
                ay = fmaf(bf_hi(vv[j]), w[j], ay);
            }
        }
        float sl = dn * dn;  // self-loop norm 1/(deg+1)
        uint32 xv = xwb[(size_t)n * 64 + lane];
        ax = fmaf(bf_lo(xv), sl, ax) + bc0;
        ay = fmaf(bf_hi(xv), sl, ay) + bc1;
        agg1b[(size_t)n * 64 + lane] = f2bf_pair(ax, ay);
        s0 += ax; q0 = fmaf(ax, ax, q0);
        s1 += ay; q1 = fmaf(ay, ay, q1);
    }

    __shared__ float ls[256];
    ls[threadIdx.x] = 0.f;
    __syncthreads();
    atomicAdd(&ls[lane * 2], s0);
    atomicAdd(&ls[lane * 2 + 1], s1);
    atomicAdd(&ls[128 + lane * 2], q0);
    atomicAdd(&ls[128 + lane * 2 + 1], q1);
    __syncthreads();
    if (threadIdx.x < 128) atomicAdd(&sums[threadIdx.x], ls[threadIdx.x]);
    else atomicAdd(&ssq[threadIdx.x - 128], ls[threadIdx.x]);
}

// ---------------- agg layer2 (D=64): half-wave per edge, packed edges, masked tail ----------------
__global__ __launch_bounds__(256) void agg64_k(const int* __restrict__ rowptr,
                                               const u64* __restrict__ edges,
                                               const float* __restrict__ dis,
                                               const uint32* __restrict__ xwb,  // 32 uint32/row
                                               const float* __restrict__ b,
                                               uint32* __restrict__ agg2b,
                                               float* __restrict__ sums,
                                               float* __restrict__ ssq) {
    const int lane = threadIdx.x & 63;
    const int half = lane >> 5;
    const int sl = lane & 31;
    const int wid = (blockIdx.x * 256 + threadIdx.x) >> 6;
    const int nwaves = gridDim.x * 4;
    float s0 = 0.f, s1 = 0.f, q0 = 0.f, q1 = 0.f;
    const float bc0 = b[sl * 2], bc1 = b[sl * 2 + 1];

    for (int n = wid; n < NN; n += nwaves) {
        const int beg = rowptr[n], end = rowptr[n + 1];
        const float dn = dis[n];
        float ax = 0.f, ay = 0.f;
        for (int e = beg; e < end; e += 16) {
            u64 ed[8]; uint32 vv[8]; float w[8];
            #pragma unroll
            for (int j = 0; j < 8; ++j) ed[j] = edges[min(e + 2 * j + half, end - 1)];
            #pragma unroll
            for (int j = 0; j < 8; ++j)
                vv[j] = xwb[(size_t)(uint32)ed[j] * 32 + sl];
            #pragma unroll
            for (int j = 0; j < 8; ++j)
                w[j] = (e + 2 * j + half < end) ? __uint_as_float((uint32)(ed[j] >> 32)) : 0.f;
            #pragma unroll
            for (int j = 0; j < 8; ++j) {
                ax = fmaf(bf_lo(vv[j]), w[j], ax);
                ay = fmaf(bf_hi(vv[j]), w[j], ay);
            }
        }
        ax += __shfl_down(ax, 32);
        ay += __shfl_down(ay, 32);
        if (half == 0) {
            float slf = dn * dn;
            uint32 xv = xwb[(size_t)n * 32 + sl];
            ax = fmaf(bf_lo(xv), slf, ax) + bc0;
            ay = fmaf(bf_hi(xv), slf, ay) + bc1;
            agg2b[(size_t)n * 32 + sl] = f2bf_pair(ax, ay);
            s0 += ax; q0 = fmaf(ax, ax, q0);
            s1 += ay; q1 = fmaf(ay, ay, q1);
        }
    }

    __shared__ float ls[128];
    if (threadIdx.x < 128) ls[threadIdx.x] = 0.f;
    __syncthreads();
    if (half == 0) {
        atomicAdd(&ls[sl * 2], s0);
        atomicAdd(&ls[sl * 2 + 1], s1);
        atomicAdd(&ls[64 + sl * 2], q0);
        atomicAdd(&ls[64 + sl * 2 + 1], q1);
    }
    __syncthreads();
    if (threadIdx.x < 64) atomicAdd(&sums[threadIdx.x], ls[threadIdx.x]);
    else if (threadIdx.x < 128) atomicAdd(&ssq[threadIdx.x - 64], ls[threadIdx.x]);
}

// ---------------- final: frozen R10 ----------------
__global__ __launch_bounds__(256) void final_k(const uint32* __restrict__ h2b,
                                               const float* __restrict__ sums,
                                               const float* __restrict__ ssq,
                                               const float* __restrict__ g,
                                               const float* __restrict__ beta,
                                               const float* __restrict__ Wf,
                                               const float* __restrict__ bf,
                                               float* __restrict__ out) {
    __shared__ float sc[64], shf[64];
    {
        int t = threadIdx.x;
        if (t < 64) {
            float m = sums[t] * (1.0f / NN);
            float var = ssq[t] * (1.0f / NN) - m * m;
            float s = g[t] * rsqrtf(var + BN_EPS);
            sc[t] = s;
            shf[t] = beta[t] - m * s;
        }
    }
    __syncthreads();
    const int lane = threadIdx.x & 63;
    const int half = lane >> 5;
    const int sl = lane & 31;
    const int node = ((blockIdx.x * 256 + threadIdx.x) >> 6) * 2 + half;
    if (node >= NN) return;
    uint32 p = h2b[(size_t)node * 32 + sl];
    float2 wf = *(const float2*)&Wf[sl * 2];
    float v = fmaxf(fmaf(bf_lo(p), sc[sl * 2], shf[sl * 2]), 0.f) * wf.x;
    v = fmaf(fmaxf(fmaf(bf_hi(p), sc[sl * 2 + 1], shf[sl * 2 + 1]), 0.f), wf.y, v);
    #pragma unroll
    for (int o = 16; o > 0; o >>= 1) v += __shfl_down(v, o, 32);
    if (sl == 0) out[node] = v + bf[0];
}

extern "C" void kernel_launch(void* const* d_in, const int* in_sizes, int n_in,
                              void* d_out, int out_size, void* d_ws, size_t ws_size,
                              hipStream_t stream) {
    const float* x   = (const float*)d_in[0];
    const int*   ei  = (const int*)d_in[1];
    const int*   src = ei;
    const int*   dst = ei + NE;
    const float* W1  = (const float*)d_in[2];
    const float* b1  = (const float*)d_in[3];
    const float* g1  = (const float*)d_in[4];
    const float* be1 = (const float*)d_in[5];
    const float* W2  = (const float*)d_in[6];
    const float* b2  = (const float*)d_in[7];
    const float* g2  = (const float*)d_in[8];
    const float* be2 = (const float*)d_in[9];
    const float* Wf  = (const float*)d_in[10];
    const float* bf  = (const float*)d_in[11];
    float* out = (float*)d_out;

    // ---- workspace layout ----
    uint32* xwb   = (uint32*)d_ws;                     // NN*64 u32 (bf16 xw, both layers)
    uint32* agg1b = xwb + (size_t)NN * 64;             // NN*64 u32 (bf16 h1 pre-BN)
    uint32* agg2b = agg1b + (size_t)NN * 64;           // NN*32 u32 (bf16 h2 pre-BN)
    float*  dis   = (float*)(agg2b + (size_t)NN * 32); // NN
    ushort* wt1   = (ushort*)(dis + NN);               // 128*128 bf16
    ushort* wt2   = wt1 + 128 * 128;                   // 64*128 bf16
    int*    rowptr = (int*)(wt2 + 64 * 128);           // NN+1
    int*    bsum   = rowptr + NN + 1;                  // 256 (pads to 8B align)
    u64*    edges  = (u64*)(((size_t)(bsum + 256) + 7) & ~(size_t)7);  // NE u64
    int*    cnt    = (int*)(edges + NE);               // NN
    int*    cur    = cnt + NN;                         // NN
    float*  sums1  = (float*)(cur + NN);               // 128
    float*  ssq1   = sums1 + D1;                       // 128
    float*  sums2  = ssq1 + D1;                        // 64
    float*  ssq2   = sums2 + D2;                       // 64

    hipMemsetAsync(cnt, 0, sizeof(int) * (2 * NN + 2 * D1 + 2 * D2), stream);

    // ---- weight prep ∥ degree count, then scan ----
    wtcnt_k<<<NB_WT + NE / 512, 256, 0, stream>>>(W1, W2, wt1, wt2, dst, cnt);
    scan1_k<<<NB_SCAN, SCAN_CHUNK, 0, stream>>>(cnt, rowptr, bsum, dis);
    scan23_k<<<(NN + 255) / 256, 256, 0, stream>>>(rowptr, bsum);

    // ---- fill (packed u64) ∥ layer-1 GEMM ----
    fillgemm_k<<<NB_FILL + NB_G1, 256, 0, stream>>>(src, dst, rowptr, dis, cur, edges,
                                                    x, wt1, (ushort*)xwb);

    // ---- layer 1 aggregate ----
    agg128_k<<<2048, 256, 0, stream>>>(rowptr, edges, dis, xwb, b1, agg1b, sums1, ssq1);

    // ---- layer 2 ----
    mgemm2_k<<<(NN + 63) / 64, 256, 0, stream>>>((const ushort*)agg1b, wt2, sums1, ssq1,
                                                 g1, be1, (ushort*)xwb);
    agg64_k<<<2048, 256, 0, stream>>>(rowptr, edges, dis, xwb, b2, agg2b, sums2, ssq2);

    // ---- final projection ----
    final_k<<<(NN / 2 + 3) / 4, 256, 0, stream>>>(agg2b, sums2, ssq2, g2, be2, Wf, bf, out);
}